// Round 10
// baseline (903.790 us; speedup 1.0000x reference)
//
#include <hip/hip_runtime.h>
#include <hip/hip_bf16.h>

// GCN v9 — UNFUSED gather (max memory-level parallelism) + LDS-free matvec.
//   g = dis ⊙ h stored bf16 (random-gather payload, 128 B/row).
//   k_gather: a[w] = relu(dis[w]*(g[w]+Σ g[r]))  -> fp32, pure load loop,
//             no LDS/fences (round-9 showed the fused matvec tail killed MLP).
//   k_mat:    o = a[w]@W+b via wave-uniform row loads + register-W column;
//             writes next g (bf16, dis-prescaled) or final fp32 relu.
//   Build (counting-sort CSR by col, parallel scan): unchanged from v8.

#define FDIM 64
#define NPART 8
#define GPB 32
#define NB 256
#define BW 512
#define MAXP 1024

typedef __hip_bfloat16 bf16;

// --- degree histogram by row, LDS-partitioned ---
__global__ void k_deg(const int* __restrict__ row, unsigned* __restrict__ part,
                      int E, int n, int psize) {
    __shared__ unsigned sh[12512];
    int p = blockIdx.x / GPB;
    int g = blockIdx.x % GPB;
    int base = p * psize;
    int lim = n - base; if (lim > psize) lim = psize;
    for (int i = threadIdx.x; i < lim; i += blockDim.x) sh[i] = 0u;
    __syncthreads();
    int stride = GPB * blockDim.x;
    for (int e = g * blockDim.x + threadIdx.x; e < E; e += stride) {
        int r = row[e] - base;
        if ((unsigned)r < (unsigned)lim) atomicAdd(&sh[r], 1u);
    }
    __syncthreads();
    unsigned* dst = part + ((size_t)p * GPB + g) * psize;
    for (int i = threadIdx.x; i < lim; i += blockDim.x) dst[i] = sh[i];
}

__global__ void k_dis(const unsigned* __restrict__ part, float* __restrict__ dis,
                      int n, int psize) {
    int i = blockIdx.x * blockDim.x + threadIdx.x;
    if (i >= n) return;
    int p = i / psize, loc = i - p * psize;
    const unsigned* src = part + (size_t)p * GPB * psize + loc;
    unsigned s = 0;
    #pragma unroll 8
    for (int g = 0; g < GPB; ++g) s += src[(size_t)g * psize];
    dis[i] = rsqrtf((float)s + 1.0f);
}

// --- coarse histogram ---
__global__ void k_chist(const int* __restrict__ col, int* __restrict__ M,
                        int E, int CH, int P) {
    __shared__ int h[MAXP];
    int b = blockIdx.x;
    for (int i = threadIdx.x; i < P; i += blockDim.x) h[i] = 0;
    __syncthreads();
    int s = b * CH, e = min(s + CH, E);
    for (int i = s + threadIdx.x; i < e; i += blockDim.x)
        atomicAdd(&h[col[i] >> 9], 1);
    __syncthreads();
    for (int p = threadIdx.x; p < P; p += blockDim.x)
        M[p * NB + b] = h[p];
}

// --- 3-phase parallel exclusive scan ---
__global__ void k_s1(int* __restrict__ M, int* __restrict__ bsum, int total) {
    __shared__ int tmp[256];
    int t = threadIdx.x;
    int i = blockIdx.x * 256 + t;
    int v = (i < total) ? M[i] : 0;
    tmp[t] = v;
    __syncthreads();
    for (int d = 1; d < 256; d <<= 1) {
        int u = (t >= d) ? tmp[t - d] : 0;
        __syncthreads();
        tmp[t] += u;
        __syncthreads();
    }
    if (i < total) M[i] = tmp[t] - v;
    if (t == 255) bsum[blockIdx.x] = tmp[255];
}

__global__ void k_s2(int* __restrict__ bsum, int nb) {
    __shared__ int tmp[256];
    int t = threadIdx.x;
    int v = (t < nb) ? bsum[t] : 0;
    tmp[t] = v;
    __syncthreads();
    for (int d = 1; d < 256; d <<= 1) {
        int u = (t >= d) ? tmp[t - d] : 0;
        __syncthreads();
        tmp[t] += u;
        __syncthreads();
    }
    if (t < nb) bsum[t] = tmp[t] - v;
}

__global__ void k_s3(int* __restrict__ M, const int* __restrict__ bsum,
                     int total, int E) {
    int i = blockIdx.x * 256 + threadIdx.x;
    if (i < total) M[i] += bsum[blockIdx.x];
    if (i == 0) M[total] = E;
}

// --- deterministic coarse scatter: s4[pos] = row<<9 | (col&511) ---
__global__ void k_cscatter(const int* __restrict__ row, const int* __restrict__ col,
                           const int* __restrict__ M, int* __restrict__ s4,
                           int E, int CH, int P) {
    __shared__ int cur[MAXP];
    int b = blockIdx.x;
    for (int p = threadIdx.x; p < P; p += blockDim.x) cur[p] = M[p * NB + b];
    __syncthreads();
    int s = b * CH, e = min(s + CH, E);
    for (int i = s + threadIdx.x; i < e; i += blockDim.x) {
        int r = row[i], c = col[i];
        int pos = atomicAdd(&cur[c >> 9], 1);
        s4[pos] = (r << 9) | (c & 511);
    }
}

// --- fine sort -> off[n+1], rows4[E] ---
__global__ void k_fsort(const int* __restrict__ s4, const int* __restrict__ M,
                        int* __restrict__ rows4, int* __restrict__ off,
                        int n, int E, int P) {
    __shared__ int hist[BW];
    __shared__ int loff[BW];
    __shared__ int tmp[256];
    int p = blockIdx.x, t = threadIdx.x;
    int gs = M[p * NB];
    int ge = (p + 1 < P) ? M[(p + 1) * NB] : E;
    int c0 = p << 9;
    int lim = n - c0; if (lim > BW) lim = BW;
    hist[2 * t] = 0; hist[2 * t + 1] = 0;
    __syncthreads();
    for (int i = gs + t; i < ge; i += 256)
        atomicAdd(&hist[s4[i] & 511], 1);
    __syncthreads();
    int s0 = hist[2 * t], s1 = hist[2 * t + 1];
    int ps = s0 + s1;
    tmp[t] = ps;
    __syncthreads();
    for (int d = 1; d < 256; d <<= 1) {
        int u = (t >= d) ? tmp[t - d] : 0;
        __syncthreads();
        tmp[t] += u;
        __syncthreads();
    }
    int ex = tmp[t] - ps;
    loff[2 * t] = ex;
    loff[2 * t + 1] = ex + s0;
    __syncthreads();
    for (int i = t; i < lim; i += 256) off[c0 + i] = gs + loff[i];
    if (p == P - 1 && t == 0) off[n] = E;
    __syncthreads();
    for (int i = gs + t; i < ge; i += 256) {
        int v = s4[i];
        int pos = gs + atomicAdd(&loff[v & 511], 1);
        rows4[pos] = v >> 9;
    }
}

// --- k_linc: g1(bf16) = dis ⊙ (concat(x,feat)@W1+b1), wave-uniform row loads ---
__global__ __launch_bounds__(256, 4)
void k_linc(const float* __restrict__ x, const float* __restrict__ feat,
            const float* __restrict__ W, const float* __restrict__ b,
            const float* __restrict__ dis, bf16* __restrict__ out,
            int n, int nwaves) {
    int t = threadIdx.x;
    int local = t >> 6, j = t & 63;
    float Wreg[FDIM];
    #pragma unroll
    for (int k = 0; k < FDIM; ++k) Wreg[k] = W[k * FDIM + j];   // column j
    float bj = b[j];
    int gw = blockIdx.x * 4 + local;
    for (int w = gw; w < n; w += nwaves) {
        const float4* xr = (const float4*)(x + (size_t)w * 32);     // uniform
        const float4* fr = (const float4*)(feat + (size_t)w * 32);  // uniform
        float o = bj;
        #pragma unroll
        for (int q = 0; q < 8; ++q) {
            float4 v = xr[q];
            o = fmaf(v.x, Wreg[4 * q + 0], o);
            o = fmaf(v.y, Wreg[4 * q + 1], o);
            o = fmaf(v.z, Wreg[4 * q + 2], o);
            o = fmaf(v.w, Wreg[4 * q + 3], o);
        }
        #pragma unroll
        for (int q = 0; q < 8; ++q) {
            float4 v = fr[q];
            o = fmaf(v.x, Wreg[32 + 4 * q + 0], o);
            o = fmaf(v.y, Wreg[32 + 4 * q + 1], o);
            o = fmaf(v.z, Wreg[32 + 4 * q + 2], o);
            o = fmaf(v.w, Wreg[32 + 4 * q + 3], o);
        }
        out[(size_t)w * FDIM + j] = __float2bfloat16(dis[w] * o);
    }
}

// --- k_gather: a[w][j] = relu(dis[w]*(g[w][j] + Σ g[r][j]))  (fp32 out) ---
__global__ __launch_bounds__(256, 4)
void k_gather(const int* __restrict__ rows4, const int* __restrict__ off,
              const float* __restrict__ dis, const bf16* __restrict__ g,
              float* __restrict__ a, int n) {
    int t = blockIdx.x * blockDim.x + threadIdx.x;
    int w = t >> 6, j = t & 63;
    if (w >= n) return;
    float acc0 = __bfloat162float(g[(size_t)w * FDIM + j]);  // self loop
    float acc1 = 0.0f;
    int k = off[w], e = off[w + 1];
    for (; k + 16 <= e; k += 16) {
        int rr[16];
        #pragma unroll
        for (int u = 0; u < 16; ++u) rr[u] = rows4[k + u];
        float hv[16];
        #pragma unroll
        for (int u = 0; u < 16; ++u)
            hv[u] = __bfloat162float(g[(size_t)rr[u] * FDIM + j]);
        #pragma unroll
        for (int u = 0; u < 16; u += 2) { acc0 += hv[u]; acc1 += hv[u + 1]; }
    }
    for (; k + 4 <= e; k += 4) {
        int r0 = rows4[k], r1 = rows4[k + 1], r2 = rows4[k + 2], r3 = rows4[k + 3];
        float h0 = __bfloat162float(g[(size_t)r0 * FDIM + j]);
        float h1 = __bfloat162float(g[(size_t)r1 * FDIM + j]);
        float h2 = __bfloat162float(g[(size_t)r2 * FDIM + j]);
        float h3 = __bfloat162float(g[(size_t)r3 * FDIM + j]);
        acc0 += h0; acc1 += h1; acc0 += h2; acc1 += h3;
    }
    for (; k < e; ++k)
        acc0 += __bfloat162float(g[(size_t)rows4[k] * FDIM + j]);
    a[(size_t)w * FDIM + j] = fmaxf(dis[w] * (acc0 + acc1), 0.0f);
}

// --- k_mat: o = a[w]@W+b; FINAL ? out=relu(o) f32 : out=bf16(dis[w]*o) ---
template <bool FINAL>
__global__ __launch_bounds__(256, 4)
void k_mat(const float* __restrict__ a, const float* __restrict__ W,
           const float* __restrict__ b, const float* __restrict__ dis,
           void* __restrict__ outp, int n, int nwaves) {
    int t = threadIdx.x;
    int local = t >> 6, j = t & 63;
    float Wreg[FDIM];
    #pragma unroll
    for (int k = 0; k < FDIM; ++k) Wreg[k] = W[k * FDIM + j];   // column j
    float bj = b[j];
    int gw = blockIdx.x * 4 + local;
    for (int w = gw; w < n; w += nwaves) {
        const float4* ar = (const float4*)(a + (size_t)w * FDIM);  // uniform
        float o = bj;
        #pragma unroll
        for (int q = 0; q < 16; ++q) {
            float4 v = ar[q];
            o = fmaf(v.x, Wreg[4 * q + 0], o);
            o = fmaf(v.y, Wreg[4 * q + 1], o);
            o = fmaf(v.z, Wreg[4 * q + 2], o);
            o = fmaf(v.w, Wreg[4 * q + 3], o);
        }
        if (FINAL) ((float*)outp)[(size_t)w * FDIM + j] = fmaxf(o, 0.0f);
        else       ((bf16*)outp)[(size_t)w * FDIM + j] = __float2bfloat16(dis[w] * o);
    }
}

extern "C" void kernel_launch(void* const* d_in, const int* in_sizes, int n_in,
                              void* d_out, int out_size, void* d_ws, size_t ws_size,
                              hipStream_t stream) {
    const float* x    = (const float*)d_in[0];
    const float* feat = (const float*)d_in[1];
    const int*   ei   = (const int*)d_in[2];
    const float* W1   = (const float*)d_in[3];
    const float* b1   = (const float*)d_in[4];
    const float* W2   = (const float*)d_in[5];
    const float* b2   = (const float*)d_in[6];
    const float* Wfc  = (const float*)d_in[7];
    const float* bfc  = (const float*)d_in[8];
    float* out = (float*)d_out;

    const int n = in_sizes[0] / 32;   // 100000
    const int E = in_sizes[2] / 2;    // 1600000
    const int* row = ei;
    const int* col = ei + E;

    const int psize = (n + NPART - 1) / NPART;   // 12500
    const int P  = (n + BW - 1) / BW;            // 196
    const int CH = (E + NB - 1) / NB;            // 6250
    const int total = P * NB;                    // 50176
    const int nb1 = (total + 255) / 256;         // 196

    // ws (ints): off[n+1] | dis[n] | M[total+1] | bsum[256] | s4[E] | rows4[E]
    //            | G(bf16 64n) | A(f32 64n)
    // part (NPART*GPB*psize u32 = 12.8 MB) aliases A (25.6 MB; consumed by
    // k_dis before A is written).
    int*   off  = (int*)d_ws;
    float* dis  = (float*)(off + (size_t)n + 1);
    int*   M    = (int*)(dis + n);
    int*   bsum = M + (size_t)total + 1;
    int*   s4    = bsum + 256;
    int*   rows4 = s4 + E;
    bf16*  G     = (bf16*)(rows4 + E);
    float* A     = (float*)(G + (size_t)n * FDIM);
    unsigned* part = (unsigned*)A;               // consumed before A written

    const int B = 256;
    const int GP = 2048;                          // persistent blocks
    const int NW = GP * 4;                        // wave stride

    // dis (deg by row)
    k_deg<<<NPART * GPB, B, 0, stream>>>(row, part, E, n, psize);
    k_dis<<<(n + B - 1) / B, B, 0, stream>>>(part, dis, n, psize);
    // CSR by col
    k_chist<<<NB, B, 0, stream>>>(col, M, E, CH, P);
    k_s1<<<nb1, B, 0, stream>>>(M, bsum, total);
    k_s2<<<1, B, 0, stream>>>(bsum, nb1);
    k_s3<<<nb1, B, 0, stream>>>(M, bsum, total, E);
    k_cscatter<<<NB, B, 0, stream>>>(row, col, M, s4, E, CH, P);
    k_fsort<<<P, B, 0, stream>>>(s4, M, rows4, off, n, E, P);

    // layer 1: g1 -> a1 -> g2 (G reused) ; layer 2: g2 -> a2 -> out
    k_linc<<<GP, B, 0, stream>>>(x, feat, W1, b1, dis, G, n, NW);
    k_gather<<<(n + 3) / 4, B, 0, stream>>>(rows4, off, dis, G, A, n);
    k_mat<false><<<GP, B, 0, stream>>>(A, W2, b2, dis, G, n, NW);
    k_gather<<<(n + 3) / 4, B, 0, stream>>>(rows4, off, dis, G, A, n);
    k_mat<true><<<GP, B, 0, stream>>>(A, Wfc, bfc, dis, out, n, NW);
}

// Round 11
// 746.378 us; speedup vs baseline: 1.2109x; 1.2109x over previous
//
#include <hip/hip_runtime.h>
#include <hip/hip_bf16.h>
#include <hip/hip_cooperative_groups.h>

namespace cg = cooperative_groups;

// GCN v10 — single cooperative build kernel (8 dispatches -> 1, grid.sync
// between phases) + proven r9 fused gather+matvec (dis-prescaled bf16 g).
//   k_build: deg-hist -> dis -> col-chist -> 3-phase scan -> coarse scatter
//            -> fine sort  (all phases in one kernel, 512 blocks x 256)
//   k_linc:  g1 = dis ⊙ (concat(x,feat)@W1+b1)        (bf16)
//   k_fused<false>: g2 = dis ⊙ (relu(dis*(Σg))@W2+b2) (bf16)
//   k_fused<true>:  out = relu(relu(dis*(Σg))@Wfc+bfc) (f32)

#define FDIM 64
#define NPART 8
#define GPB 64
#define CB (NPART * GPB)   // 512 cooperative blocks (2/CU at 50KB LDS)
#define NB 512             // edge chunks == CB
#define BW 512             // cols per coarse bucket

typedef __hip_bfloat16 bf16;

__global__ void __launch_bounds__(256, 2)
k_build(const int* __restrict__ row, const int* __restrict__ col,
        unsigned* __restrict__ part, float* __restrict__ dis,
        int* __restrict__ M, int* __restrict__ bsum,
        int2* __restrict__ s8, int* __restrict__ rows4, int* __restrict__ off,
        int n, int E, int psize, int P, int CH, int total) {
    cg::grid_group grid = cg::this_grid();
    __shared__ int sm[12512];                 // 50 KB, reused per phase
    int t = threadIdx.x, b = blockIdx.x;

    // --- phase 1: deg partial histograms (8 partitions x 64 blocks) ---
    {
        int p = b >> 6, g = b & 63;
        int base = p * psize;
        int lim = n - base; if (lim > psize) lim = psize;
        unsigned* sh = (unsigned*)sm;
        for (int i = t; i < lim; i += 256) sh[i] = 0u;
        __syncthreads();
        for (int e = g * 256 + t; e < E; e += GPB * 256) {
            int r = row[e] - base;
            if ((unsigned)r < (unsigned)lim) atomicAdd(&sh[r], 1u);
        }
        __syncthreads();
        unsigned* dst = part + ((size_t)p * GPB + g) * psize;
        for (int i = t; i < lim; i += 256) dst[i] = sh[i];
    }
    grid.sync();

    // --- phase 2: dis = rsqrt(deg+1)  (grid-stride; no sm use) ---
    for (int i = b * 256 + t; i < n; i += CB * 256) {
        int p = i / psize, loc = i - p * psize;
        const unsigned* src = part + (size_t)p * GPB * psize + loc;
        unsigned s = 0;
        #pragma unroll 8
        for (int g = 0; g < GPB; ++g) s += src[(size_t)g * psize];
        dis[i] = rsqrtf((float)s + 1.0f);
    }

    // --- phase 3: coarse col histogram M[p*NB + b] (chunk b of CB) ---
    {
        __syncthreads();
        for (int i = t; i < P; i += 256) sm[i] = 0;
        __syncthreads();
        int s = b * CH, e = min(s + CH, E);
        for (int i = s + t; i < e; i += 256)
            atomicAdd(&sm[col[i] >> 9], 1);
        __syncthreads();
        for (int p = t; p < P; p += 256) M[p * NB + b] = sm[p];
    }
    grid.sync();

    // --- phase 4: scan pass 1 (per-256-chunk exclusive + block sums) ---
    int nb1 = (total + 255) >> 8;             // 392 <= 512
    if (b < nb1) {
        __syncthreads();
        int i = b * 256 + t;
        int v = (i < total) ? M[i] : 0;
        sm[t] = v;
        __syncthreads();
        for (int d = 1; d < 256; d <<= 1) {
            int u = (t >= d) ? sm[t - d] : 0;
            __syncthreads(); sm[t] += u; __syncthreads();
        }
        if (i < total) M[i] = sm[t] - v;
        if (t == 255) bsum[b] = sm[255];
    }
    grid.sync();

    // --- phase 5: scan block sums (single block, 2 elems/thread) ---
    if (b == 0) {
        __syncthreads();
        int v0 = (2 * t < nb1) ? bsum[2 * t] : 0;
        int v1 = (2 * t + 1 < nb1) ? bsum[2 * t + 1] : 0;
        int ps = v0 + v1;
        sm[t] = ps;
        __syncthreads();
        for (int d = 1; d < 256; d <<= 1) {
            int u = (t >= d) ? sm[t - d] : 0;
            __syncthreads(); sm[t] += u; __syncthreads();
        }
        int ex = sm[t] - ps;
        if (2 * t < nb1) bsum[2 * t] = ex;
        if (2 * t + 1 < nb1) bsum[2 * t + 1] = ex + v0;
    }
    grid.sync();

    // --- phase 6: add back block sums + sentinel ---
    if (b < nb1) {
        int i = b * 256 + t;
        if (i < total) M[i] += bsum[b];
        if (i == 0) M[total] = E;
    }
    grid.sync();

    // --- phase 7: deterministic coarse scatter (chunk b) ---
    {
        __syncthreads();
        for (int p = t; p < P; p += 256) sm[p] = M[p * NB + b];
        __syncthreads();
        int s = b * CH, e = min(s + CH, E);
        for (int i = s + t; i < e; i += 256) {
            int r = row[i], c = col[i];
            int pos = atomicAdd(&sm[c >> 9], 1);
            s8[pos] = make_int2(r, c);
        }
    }
    grid.sync();

    // --- phase 8: fine sort within bucket -> off[n+1], rows4[E] ---
    if (b < P) {
        int* hist = sm;
        int* loff = sm + BW;
        int* tmp  = sm + 2 * BW;
        __syncthreads();
        int gs = M[b * NB];
        int ge = (b + 1 < P) ? M[(b + 1) * NB] : E;
        int c0 = b << 9;
        int lim = n - c0; if (lim > BW) lim = BW;
        hist[2 * t] = 0; hist[2 * t + 1] = 0;
        __syncthreads();
        for (int i = gs + t; i < ge; i += 256)
            atomicAdd(&hist[s8[i].y - c0], 1);
        __syncthreads();
        int s0 = hist[2 * t], s1v = hist[2 * t + 1];
        int ps = s0 + s1v;
        tmp[t] = ps;
        __syncthreads();
        for (int d = 1; d < 256; d <<= 1) {
            int u = (t >= d) ? tmp[t - d] : 0;
            __syncthreads(); tmp[t] += u; __syncthreads();
        }
        int ex = tmp[t] - ps;
        loff[2 * t] = ex;
        loff[2 * t + 1] = ex + s0;
        __syncthreads();
        for (int i = t; i < lim; i += 256) off[c0 + i] = gs + loff[i];
        if (b == P - 1 && t == 0) off[n] = E;
        __syncthreads();
        for (int i = gs + t; i < ge; i += 256) {
            int2 rc = s8[i];
            int pos = gs + atomicAdd(&loff[rc.y - c0], 1);
            rows4[pos] = rc.x;
        }
    }
}

// --- k_linc: g1(bf16) = dis ⊙ (concat(x,feat)@W1+b1)  (proven r8/r9 form) ---
__global__ __launch_bounds__(256, 4)
void k_linc(const float* __restrict__ x, const float* __restrict__ feat,
            const float* __restrict__ W, const float* __restrict__ b,
            const float* __restrict__ dis, bf16* __restrict__ out,
            int n, int nwaves) {
    __shared__ float sIn[4][FDIM];
    int t = threadIdx.x;
    int local = t >> 6, j = t & 63;
    float Wreg[FDIM];
    #pragma unroll
    for (int k = 0; k < FDIM; ++k) Wreg[k] = W[k * FDIM + j];   // column j (AGPRs)
    float bj = b[j];
    int gw = blockIdx.x * 4 + local;
    for (int w = gw; w < n; w += nwaves) {
        sIn[local][j] = (j < 32) ? x[(size_t)w * 32 + j]
                                 : feat[(size_t)w * 32 + (j - 32)];
        __threadfence_block();
        float o = bj;
        #pragma unroll
        for (int k4 = 0; k4 < 16; ++k4) {
            float4 h4 = *(const float4*)&sIn[local][k4 * 4];
            o = fmaf(h4.x, Wreg[4 * k4 + 0], o);
            o = fmaf(h4.y, Wreg[4 * k4 + 1], o);
            o = fmaf(h4.z, Wreg[4 * k4 + 2], o);
            o = fmaf(h4.w, Wreg[4 * k4 + 3], o);
        }
        out[(size_t)w * FDIM + j] = __float2bfloat16(dis[w] * o);
        __threadfence_block();
    }
}

// --- fused: a = relu(dc*(g[w]+Σg[r])); o = a@W+b  (proven r9 form) ---
template <bool FINAL>
__global__ __launch_bounds__(256, 4)
void k_fused(const int* __restrict__ rows4, const int* __restrict__ off,
             const float* __restrict__ dis, const bf16* __restrict__ g,
             const float* __restrict__ W, const float* __restrict__ b,
             void* __restrict__ outp, int n, int nwaves) {
    __shared__ float sIn[4][FDIM];
    int t = threadIdx.x;
    int local = t >> 6, j = t & 63;
    float Wreg[FDIM];
    #pragma unroll
    for (int k = 0; k < FDIM; ++k) Wreg[k] = W[k * FDIM + j];   // column j (AGPRs)
    float bj = b[j];
    int gw = blockIdx.x * 4 + local;
    for (int w = gw; w < n; w += nwaves) {
        float dc = dis[w];
        float acc0 = __bfloat162float(g[(size_t)w * FDIM + j]);  // self loop
        float acc1 = 0.0f;
        int k = off[w], e = off[w + 1];
        for (; k + 16 <= e; k += 16) {
            int rr[16];
            #pragma unroll
            for (int u = 0; u < 16; ++u) rr[u] = rows4[k + u];
            float hv[16];
            #pragma unroll
            for (int u = 0; u < 16; ++u)
                hv[u] = __bfloat162float(g[(size_t)rr[u] * FDIM + j]);
            #pragma unroll
            for (int u = 0; u < 16; u += 2) { acc0 += hv[u]; acc1 += hv[u + 1]; }
        }
        for (; k + 4 <= e; k += 4) {
            int r0 = rows4[k], r1 = rows4[k + 1], r2 = rows4[k + 2], r3 = rows4[k + 3];
            float h0 = __bfloat162float(g[(size_t)r0 * FDIM + j]);
            float h1 = __bfloat162float(g[(size_t)r1 * FDIM + j]);
            float h2 = __bfloat162float(g[(size_t)r2 * FDIM + j]);
            float h3 = __bfloat162float(g[(size_t)r3 * FDIM + j]);
            acc0 += h0; acc1 += h1; acc0 += h2; acc1 += h3;
        }
        for (; k < e; ++k)
            acc0 += __bfloat162float(g[(size_t)rows4[k] * FDIM + j]);
        sIn[local][j] = fmaxf(dc * (acc0 + acc1), 0.0f);     // mid relu
        __threadfence_block();
        float o = bj;
        #pragma unroll
        for (int k4 = 0; k4 < 16; ++k4) {
            float4 h4 = *(const float4*)&sIn[local][k4 * 4];
            o = fmaf(h4.x, Wreg[4 * k4 + 0], o);
            o = fmaf(h4.y, Wreg[4 * k4 + 1], o);
            o = fmaf(h4.z, Wreg[4 * k4 + 2], o);
            o = fmaf(h4.w, Wreg[4 * k4 + 3], o);
        }
        if (FINAL) ((float*)outp)[(size_t)w * FDIM + j] = fmaxf(o, 0.0f);
        else       ((bf16*)outp)[(size_t)w * FDIM + j] = __float2bfloat16(dc * o);
        __threadfence_block();
    }
}

extern "C" void kernel_launch(void* const* d_in, const int* in_sizes, int n_in,
                              void* d_out, int out_size, void* d_ws, size_t ws_size,
                              hipStream_t stream) {
    const float* x    = (const float*)d_in[0];
    const float* feat = (const float*)d_in[1];
    const int*   ei   = (const int*)d_in[2];
    const float* W1   = (const float*)d_in[3];
    const float* b1   = (const float*)d_in[4];
    const float* W2   = (const float*)d_in[5];
    const float* b2   = (const float*)d_in[6];
    const float* Wfc  = (const float*)d_in[7];
    const float* bfc  = (const float*)d_in[8];
    float* out = (float*)d_out;

    int n = in_sizes[0] / 32;   // 100000
    int E = in_sizes[2] / 2;    // 1600000
    const int* row = ei;
    const int* col = ei + E;

    int psize = (n + NPART - 1) / NPART;   // 12500 (<= 12512 LDS)
    int P  = (n + BW - 1) / BW;            // 196
    int CH = (E + NB - 1) / NB;            // 3125
    int total = P * NB;                    // 100352

    // ws: off[n+1] | dis[n] | M[total+1] | bsum[512] | pad | s8[2E] | rows4[E]
    //     | bufA(bf16 64n) | bufB(bf16 64n); part aliases bufA+bufB (25.6 MB,
    //     consumed in build phase 2 before bufs are written).
    int*   off  = (int*)d_ws;
    float* dis  = (float*)(off + (size_t)n + 1);
    int*   M    = (int*)(dis + n);
    int*   bsum = M + (size_t)total + 1;
    size_t co   = (size_t)n + 1 + n + total + 1 + 512;
    co += (co & 1);
    int2*  s8    = (int2*)((int*)d_ws + co);
    int*   rows4 = (int*)(s8 + E);
    bf16*  bufA  = (bf16*)(rows4 + E);
    bf16*  bufB  = bufA + (size_t)n * FDIM;
    unsigned* part = (unsigned*)bufA;

    const int B = 256;
    const int GP = 2048;
    const int NW = GP * 4;

    // --- single cooperative build dispatch ---
    void* args[] = { (void*)&row, (void*)&col, (void*)&part, (void*)&dis,
                     (void*)&M, (void*)&bsum, (void*)&s8, (void*)&rows4,
                     (void*)&off, (void*)&n, (void*)&E, (void*)&psize,
                     (void*)&P, (void*)&CH, (void*)&total };
    hipLaunchCooperativeKernel((const void*)k_build, dim3(CB), dim3(B),
                               args, 0, stream);

    // g1 = dis⊙(concat@W1+b1); g2 = dis⊙(relu(dis*Σ)@W2+b2); out = relu(...)
    k_linc<<<GP, B, 0, stream>>>(x, feat, W1, b1, dis, bufA, n, NW);
    k_fused<false><<<GP, B, 0, stream>>>(rows4, off, dis, bufA, W2, b2, bufB, n, NW);
    k_fused<true><<<GP, B, 0, stream>>>(rows4, off, dis, bufB, Wfc, bfc, out, n, NW);
}

// Round 12
// 358.951 us; speedup vs baseline: 2.5179x; 2.0793x over previous
//
#include <hip/hip_runtime.h>
#include <hip/hip_bf16.h>

// GCN v11 — 6 dispatches. Independent phases share dispatches (block-range
// split, kernel boundary = the only sync); scan fix-up kernels eliminated
// algebraically (chunk p == bucket p, so consumers re-scan bsum[196] in LDS).
//   k_h:   deg partial hist (512 blk) ∥ coarse col hist (256 blk)
//   k_ds1: dis (391 blk) ∥ scan pass 1 (196 blk)
//   k_csc: coarse scatter (inline bsum scan)
//   k_fl:  fine sort (196 blk) ∥ k_linc (1024 blk)
//   k_fused<false>, k_fused<true>: proven r9 forms (97.5 µs each)

#define FDIM 64
#define NPART 8
#define GPB 64
#define NB 256
#define BW 512
#define MAXP 1024
#define GPLIN 1024

typedef __hip_bfloat16 bf16;

// --- dispatch 1: deg partial histograms ∥ coarse col histogram ---
__global__ void k_h(const int* __restrict__ row, const int* __restrict__ col,
                    unsigned* __restrict__ part, int* __restrict__ M,
                    int E, int n, int psize, int P, int CH) {
    __shared__ unsigned sm[12512];            // 50 KB
    int t = threadIdx.x, b = blockIdx.x;
    if (b < NPART * GPB) {                    // deg partials
        int p = b >> 6, g = b & 63;
        int base = p * psize;
        int lim = n - base; if (lim > psize) lim = psize;
        for (int i = t; i < lim; i += 256) sm[i] = 0u;
        __syncthreads();
        for (int e = g * 256 + t; e < E; e += GPB * 256) {
            int r = row[e] - base;
            if ((unsigned)r < (unsigned)lim) atomicAdd(&sm[r], 1u);
        }
        __syncthreads();
        unsigned* dst = part + ((size_t)p * GPB + g) * psize;
        for (int i = t; i < lim; i += 256) dst[i] = sm[i];
    } else {                                  // coarse col histogram, chunk cb
        int cb = b - NPART * GPB;
        int* h = (int*)sm;
        for (int i = t; i < P; i += 256) h[i] = 0;
        __syncthreads();
        int s = cb * CH, e = min(s + CH, E);
        for (int i = s + t; i < e; i += 256)
            atomicAdd(&h[col[i] >> 9], 1);
        __syncthreads();
        for (int p = t; p < P; p += 256) M[p * NB + cb] = h[p];
    }
}

// --- dispatch 2: dis ∥ scan pass 1 (in-chunk exclusive + bucket totals) ---
__global__ void k_ds1(const unsigned* __restrict__ part, float* __restrict__ dis,
                      int* __restrict__ M, int* __restrict__ bsum,
                      int n, int psize, int ndis, int P) {
    __shared__ int sc[256];
    int t = threadIdx.x, b = blockIdx.x;
    if (b < ndis) {                           // dis
        int i = b * 256 + t;
        if (i >= n) return;
        int p = i / psize, loc = i - p * psize;
        const unsigned* src = part + (size_t)p * GPB * psize + loc;
        unsigned s = 0;
        #pragma unroll 8
        for (int g = 0; g < GPB; ++g) s += src[(size_t)g * psize];
        dis[i] = rsqrtf((float)s + 1.0f);
    } else {                                  // scan chunk sb (== bucket sb)
        int sb = b - ndis;                    // 0..P-1
        int i = sb * 256 + t;                 // total = P*256, always valid
        int v = M[i];
        sc[t] = v;
        __syncthreads();
        for (int d = 1; d < 256; d <<= 1) {
            int u = (t >= d) ? sc[t - d] : 0;
            __syncthreads(); sc[t] += u; __syncthreads();
        }
        M[i] = sc[t] - v;                     // exclusive within bucket-row
        if (t == 255) bsum[sb] = sc[255];     // bucket total (raw)
    }
}

// --- dispatch 3: coarse scatter (chunk b), bsum scanned inline ---
__global__ void k_csc(const int* __restrict__ row, const int* __restrict__ col,
                      const int* __restrict__ M, const int* __restrict__ bsum,
                      int* __restrict__ s4, int E, int CH, int P) {
    __shared__ int sc[256];
    __shared__ int bs[256];
    __shared__ int cur[MAXP];
    int t = threadIdx.x, b = blockIdx.x;
    int v = (t < P) ? bsum[t] : 0;            // P=196 <= 256
    sc[t] = v;
    __syncthreads();
    for (int d = 1; d < 256; d <<= 1) {
        int u = (t >= d) ? sc[t - d] : 0;
        __syncthreads(); sc[t] += u; __syncthreads();
    }
    bs[t] = sc[t] - v;                        // exclusive bucket starts
    __syncthreads();
    for (int p = t; p < P; p += 256) cur[p] = bs[p] + M[p * NB + b];
    __syncthreads();
    int s = b * CH, e = min(s + CH, E);
    for (int i = s + t; i < e; i += 256) {
        int r = row[i], c = col[i];
        int pos = atomicAdd(&cur[c >> 9], 1);
        s4[pos] = (r << 9) | (c & 511);
    }
}

// --- dispatch 4: fine sort (blocks < P) ∥ k_linc (blocks >= P) ---
__global__ __launch_bounds__(256, 4)
void k_fl(const int* __restrict__ s4, const int* __restrict__ M,
          const int* __restrict__ bsum, int* __restrict__ rows4,
          int* __restrict__ off,
          const float* __restrict__ x, const float* __restrict__ feat,
          const float* __restrict__ W, const float* __restrict__ bvec,
          const float* __restrict__ dis, bf16* __restrict__ g1,
          int n, int E, int P) {
    __shared__ int sc[256];
    __shared__ int bs[256];
    __shared__ int hist[BW];
    __shared__ int loff[BW];
    __shared__ int tmp[256];
    __shared__ float sIn[4][FDIM];
    int t = threadIdx.x, b = blockIdx.x;
    if (b < P) {                              // fine sort bucket b
        int v = (t < P) ? bsum[t] : 0;
        sc[t] = v;
        __syncthreads();
        for (int d = 1; d < 256; d <<= 1) {
            int u = (t >= d) ? sc[t - d] : 0;
            __syncthreads(); sc[t] += u; __syncthreads();
        }
        bs[t] = sc[t] - v;
        __syncthreads();
        int gs = bs[b];
        int ge = gs + bsum[b];
        int c0 = b << 9;
        int lim = n - c0; if (lim > BW) lim = BW;
        hist[2 * t] = 0; hist[2 * t + 1] = 0;
        __syncthreads();
        for (int i = gs + t; i < ge; i += 256)
            atomicAdd(&hist[s4[i] & 511], 1);
        __syncthreads();
        int s0 = hist[2 * t], s1v = hist[2 * t + 1];
        int ps = s0 + s1v;
        tmp[t] = ps;
        __syncthreads();
        for (int d = 1; d < 256; d <<= 1) {
            int u = (t >= d) ? tmp[t - d] : 0;
            __syncthreads(); tmp[t] += u; __syncthreads();
        }
        int ex = tmp[t] - ps;
        loff[2 * t] = ex;
        loff[2 * t + 1] = ex + s0;
        __syncthreads();
        for (int i = t; i < lim; i += 256) off[c0 + i] = gs + loff[i];
        if (b == P - 1 && t == 0) off[n] = E;
        __syncthreads();
        for (int i = gs + t; i < ge; i += 256) {
            int v2 = s4[i];
            int pos = gs + atomicAdd(&loff[v2 & 511], 1);
            rows4[pos] = v2 >> 9;
        }
    } else {                                  // k_linc (r9 proven form)
        int local = t >> 6, j = t & 63;
        float Wreg[FDIM];
        #pragma unroll
        for (int k = 0; k < FDIM; ++k) Wreg[k] = W[k * FDIM + j];
        float bj = bvec[j];
        int gw = (b - P) * 4 + local;
        int nwl = GPLIN * 4;
        for (int w = gw; w < n; w += nwl) {
            sIn[local][j] = (j < 32) ? x[(size_t)w * 32 + j]
                                     : feat[(size_t)w * 32 + (j - 32)];
            __threadfence_block();
            float o = bj;
            #pragma unroll
            for (int k4 = 0; k4 < 16; ++k4) {
                float4 h4 = *(const float4*)&sIn[local][k4 * 4];
                o = fmaf(h4.x, Wreg[4 * k4 + 0], o);
                o = fmaf(h4.y, Wreg[4 * k4 + 1], o);
                o = fmaf(h4.z, Wreg[4 * k4 + 2], o);
                o = fmaf(h4.w, Wreg[4 * k4 + 3], o);
            }
            g1[(size_t)w * FDIM + j] = __float2bfloat16(dis[w] * o);
            __threadfence_block();
        }
    }
}

// --- fused: a = relu(dc*(g[w]+Σg[r])); o = a@W+b  (r9 proven, 97.5 µs) ---
template <bool FINAL>
__global__ __launch_bounds__(256, 4)
void k_fused(const int* __restrict__ rows4, const int* __restrict__ off,
             const float* __restrict__ dis, const bf16* __restrict__ g,
             const float* __restrict__ W, const float* __restrict__ b,
             void* __restrict__ outp, int n, int nwaves) {
    __shared__ float sIn[4][FDIM];
    int t = threadIdx.x;
    int local = t >> 6, j = t & 63;
    float Wreg[FDIM];
    #pragma unroll
    for (int k = 0; k < FDIM; ++k) Wreg[k] = W[k * FDIM + j];
    float bj = b[j];
    int gw = blockIdx.x * 4 + local;
    for (int w = gw; w < n; w += nwaves) {
        float dc = dis[w];
        float acc0 = __bfloat162float(g[(size_t)w * FDIM + j]);  // self loop
        float acc1 = 0.0f;
        int k = off[w], e = off[w + 1];
        for (; k + 16 <= e; k += 16) {
            int rr[16];
            #pragma unroll
            for (int u = 0; u < 16; ++u) rr[u] = rows4[k + u];
            float hv[16];
            #pragma unroll
            for (int u = 0; u < 16; ++u)
                hv[u] = __bfloat162float(g[(size_t)rr[u] * FDIM + j]);
            #pragma unroll
            for (int u = 0; u < 16; u += 2) { acc0 += hv[u]; acc1 += hv[u + 1]; }
        }
        for (; k + 4 <= e; k += 4) {
            int r0 = rows4[k], r1 = rows4[k + 1], r2 = rows4[k + 2], r3 = rows4[k + 3];
            float h0 = __bfloat162float(g[(size_t)r0 * FDIM + j]);
            float h1 = __bfloat162float(g[(size_t)r1 * FDIM + j]);
            float h2 = __bfloat162float(g[(size_t)r2 * FDIM + j]);
            float h3 = __bfloat162float(g[(size_t)r3 * FDIM + j]);
            acc0 += h0; acc1 += h1; acc0 += h2; acc1 += h3;
        }
        for (; k < e; ++k)
            acc0 += __bfloat162float(g[(size_t)rows4[k] * FDIM + j]);
        sIn[local][j] = fmaxf(dc * (acc0 + acc1), 0.0f);     // mid relu
        __threadfence_block();
        float o = bj;
        #pragma unroll
        for (int k4 = 0; k4 < 16; ++k4) {
            float4 h4 = *(const float4*)&sIn[local][k4 * 4];
            o = fmaf(h4.x, Wreg[4 * k4 + 0], o);
            o = fmaf(h4.y, Wreg[4 * k4 + 1], o);
            o = fmaf(h4.z, Wreg[4 * k4 + 2], o);
            o = fmaf(h4.w, Wreg[4 * k4 + 3], o);
        }
        if (FINAL) ((float*)outp)[(size_t)w * FDIM + j] = fmaxf(o, 0.0f);
        else       ((bf16*)outp)[(size_t)w * FDIM + j] = __float2bfloat16(dc * o);
        __threadfence_block();
    }
}

extern "C" void kernel_launch(void* const* d_in, const int* in_sizes, int n_in,
                              void* d_out, int out_size, void* d_ws, size_t ws_size,
                              hipStream_t stream) {
    const float* x    = (const float*)d_in[0];
    const float* feat = (const float*)d_in[1];
    const int*   ei   = (const int*)d_in[2];
    const float* W1   = (const float*)d_in[3];
    const float* b1   = (const float*)d_in[4];
    const float* W2   = (const float*)d_in[5];
    const float* b2   = (const float*)d_in[6];
    const float* Wfc  = (const float*)d_in[7];
    const float* bfc  = (const float*)d_in[8];
    float* out = (float*)d_out;

    const int n = in_sizes[0] / 32;   // 100000
    const int E = in_sizes[2] / 2;    // 1600000
    const int* row = ei;
    const int* col = ei + E;

    const int psize = (n + NPART - 1) / NPART;   // 12500
    const int P  = (n + BW - 1) / BW;            // 196
    const int CH = (E + NB - 1) / NB;            // 6250
    const int total = P * NB;                    // 50176
    const int ndis = (n + 255) / 256;            // 391

    // ws: off[n+1] | dis[n] | M[total] | bsum[256] | s4[E] | rows4[E]
    //     | bufA(bf16 64n) | bufB(bf16 64n)
    // part (512*psize u32 = 25.6 MB) aliases bufA+bufB (25.6 MB, consumed in
    // k_ds1 before bufA is written by k_fl's linc half).
    int*   off  = (int*)d_ws;
    float* dis  = (float*)(off + (size_t)n + 1);
    int*   M    = (int*)(dis + n);
    int*   bsum = M + (size_t)total;
    int*   s4    = bsum + 256;
    int*   rows4 = s4 + E;
    bf16*  bufA  = (bf16*)(rows4 + E);
    bf16*  bufB  = bufA + (size_t)n * FDIM;
    unsigned* part = (unsigned*)bufA;

    const int B = 256;
    const int GP = 2048;
    const int NW = GP * 4;

    k_h<<<NPART * GPB + NB, B, 0, stream>>>(row, col, part, M, E, n, psize, P, CH);
    k_ds1<<<ndis + P, B, 0, stream>>>(part, dis, M, bsum, n, psize, ndis, P);
    k_csc<<<NB, B, 0, stream>>>(row, col, M, bsum, s4, E, CH, P);
    k_fl<<<P + GPLIN, B, 0, stream>>>(s4, M, bsum, rows4, off,
                                      x, feat, W1, b1, dis, bufA, n, E, P);
    k_fused<false><<<GP, B, 0, stream>>>(rows4, off, dis, bufA, W2, b2, bufB, n, NW);
    k_fused<true><<<GP, B, 0, stream>>>(rows4, off, dis, bufB, Wfc, bfc, out, n, NW);
}

// Round 13
// 314.334 us; speedup vs baseline: 2.8753x; 1.1419x over previous
//
#include <hip/hip_runtime.h>
#include <hip/hip_bf16.h>

// GCN v12 — unfused lean gather (8 waves/EU) + MFMA matvec.
//   k_gather: a = relu(dis*(g[w]+Σg[r])) bf16, minimal VGPR, max occupancy
//             (r5 evidence: lean gather sustains 3.75 TB/s vs fused 1.8).
//   k_mat:    [100k,64]@[64,64] via mfma_f32_16x16x32_bf16; W bf16-cast and
//             transposed into LDS once per persistent block; B-frags in regs.
//   Build (r12's 4 merged dispatches): unchanged.

#define FDIM 64
#define NPART 8
#define GPB 64
#define NB 256
#define BW 512
#define MAXP 1024
#define GPLIN 1024

typedef __hip_bfloat16 bf16;
typedef short v8s __attribute__((ext_vector_type(8)));
typedef float v4f __attribute__((ext_vector_type(4)));

// --- dispatch 1: deg partial histograms ∥ coarse col histogram ---
__global__ void k_h(const int* __restrict__ row, const int* __restrict__ col,
                    unsigned* __restrict__ part, int* __restrict__ M,
                    int E, int n, int psize, int P, int CH) {
    __shared__ unsigned sm[12512];
    int t = threadIdx.x, b = blockIdx.x;
    if (b < NPART * GPB) {
        int p = b >> 6, g = b & 63;
        int base = p * psize;
        int lim = n - base; if (lim > psize) lim = psize;
        for (int i = t; i < lim; i += 256) sm[i] = 0u;
        __syncthreads();
        for (int e = g * 256 + t; e < E; e += GPB * 256) {
            int r = row[e] - base;
            if ((unsigned)r < (unsigned)lim) atomicAdd(&sm[r], 1u);
        }
        __syncthreads();
        unsigned* dst = part + ((size_t)p * GPB + g) * psize;
        for (int i = t; i < lim; i += 256) dst[i] = sm[i];
    } else {
        int cb = b - NPART * GPB;
        int* h = (int*)sm;
        for (int i = t; i < P; i += 256) h[i] = 0;
        __syncthreads();
        int s = cb * CH, e = min(s + CH, E);
        for (int i = s + t; i < e; i += 256)
            atomicAdd(&h[col[i] >> 9], 1);
        __syncthreads();
        for (int p = t; p < P; p += 256) M[p * NB + cb] = h[p];
    }
}

// --- dispatch 2: dis ∥ scan pass 1 ---
__global__ void k_ds1(const unsigned* __restrict__ part, float* __restrict__ dis,
                      int* __restrict__ M, int* __restrict__ bsum,
                      int n, int psize, int ndis, int P) {
    __shared__ int sc[256];
    int t = threadIdx.x, b = blockIdx.x;
    if (b < ndis) {
        int i = b * 256 + t;
        if (i >= n) return;
        int p = i / psize, loc = i - p * psize;
        const unsigned* src = part + (size_t)p * GPB * psize + loc;
        unsigned s = 0;
        #pragma unroll 8
        for (int g = 0; g < GPB; ++g) s += src[(size_t)g * psize];
        dis[i] = rsqrtf((float)s + 1.0f);
    } else {
        int sb = b - ndis;
        int i = sb * 256 + t;
        int v = M[i];
        sc[t] = v;
        __syncthreads();
        for (int d = 1; d < 256; d <<= 1) {
            int u = (t >= d) ? sc[t - d] : 0;
            __syncthreads(); sc[t] += u; __syncthreads();
        }
        M[i] = sc[t] - v;
        if (t == 255) bsum[sb] = sc[255];
    }
}

// --- dispatch 3: coarse scatter (inline bsum scan) ---
__global__ void k_csc(const int* __restrict__ row, const int* __restrict__ col,
                      const int* __restrict__ M, const int* __restrict__ bsum,
                      int* __restrict__ s4, int E, int CH, int P) {
    __shared__ int sc[256];
    __shared__ int bs[256];
    __shared__ int cur[MAXP];
    int t = threadIdx.x, b = blockIdx.x;
    int v = (t < P) ? bsum[t] : 0;
    sc[t] = v;
    __syncthreads();
    for (int d = 1; d < 256; d <<= 1) {
        int u = (t >= d) ? sc[t - d] : 0;
        __syncthreads(); sc[t] += u; __syncthreads();
    }
    bs[t] = sc[t] - v;
    __syncthreads();
    for (int p = t; p < P; p += 256) cur[p] = bs[p] + M[p * NB + b];
    __syncthreads();
    int s = b * CH, e = min(s + CH, E);
    for (int i = s + t; i < e; i += 256) {
        int r = row[i], c = col[i];
        int pos = atomicAdd(&cur[c >> 9], 1);
        s4[pos] = (r << 9) | (c & 511);
    }
}

// --- dispatch 4: fine sort (blocks < P) ∥ k_linc (blocks >= P) ---
__global__ __launch_bounds__(256, 4)
void k_fl(const int* __restrict__ s4, const int* __restrict__ M,
          const int* __restrict__ bsum, int* __restrict__ rows4,
          int* __restrict__ off,
          const float* __restrict__ x, const float* __restrict__ feat,
          const float* __restrict__ W, const float* __restrict__ bvec,
          const float* __restrict__ dis, bf16* __restrict__ g1,
          int n, int E, int P) {
    __shared__ int sc[256];
    __shared__ int bs[256];
    __shared__ int hist[BW];
    __shared__ int loff[BW];
    __shared__ int tmp[256];
    __shared__ float sIn[4][FDIM];
    int t = threadIdx.x, b = blockIdx.x;
    if (b < P) {
        int v = (t < P) ? bsum[t] : 0;
        sc[t] = v;
        __syncthreads();
        for (int d = 1; d < 256; d <<= 1) {
            int u = (t >= d) ? sc[t - d] : 0;
            __syncthreads(); sc[t] += u; __syncthreads();
        }
        bs[t] = sc[t] - v;
        __syncthreads();
        int gs = bs[b];
        int ge = gs + bsum[b];
        int c0 = b << 9;
        int lim = n - c0; if (lim > BW) lim = BW;
        hist[2 * t] = 0; hist[2 * t + 1] = 0;
        __syncthreads();
        for (int i = gs + t; i < ge; i += 256)
            atomicAdd(&hist[s4[i] & 511], 1);
        __syncthreads();
        int s0 = hist[2 * t], s1v = hist[2 * t + 1];
        int ps = s0 + s1v;
        tmp[t] = ps;
        __syncthreads();
        for (int d = 1; d < 256; d <<= 1) {
            int u = (t >= d) ? tmp[t - d] : 0;
            __syncthreads(); tmp[t] += u; __syncthreads();
        }
        int ex = tmp[t] - ps;
        loff[2 * t] = ex;
        loff[2 * t + 1] = ex + s0;
        __syncthreads();
        for (int i = t; i < lim; i += 256) off[c0 + i] = gs + loff[i];
        if (b == P - 1 && t == 0) off[n] = E;
        __syncthreads();
        for (int i = gs + t; i < ge; i += 256) {
            int v2 = s4[i];
            int pos = gs + atomicAdd(&loff[v2 & 511], 1);
            rows4[pos] = v2 >> 9;
        }
    } else {                                  // k_linc (r9 proven form)
        int local = t >> 6, j = t & 63;
        float Wreg[FDIM];
        #pragma unroll
        for (int k = 0; k < FDIM; ++k) Wreg[k] = W[k * FDIM + j];
        float bj = bvec[j];
        int gw = (b - P) * 4 + local;
        int nwl = GPLIN * 4;
        for (int w = gw; w < n; w += nwl) {
            sIn[local][j] = (j < 32) ? x[(size_t)w * 32 + j]
                                     : feat[(size_t)w * 32 + (j - 32)];
            __threadfence_block();
            float o = bj;
            #pragma unroll
            for (int k4 = 0; k4 < 16; ++k4) {
                float4 h4 = *(const float4*)&sIn[local][k4 * 4];
                o = fmaf(h4.x, Wreg[4 * k4 + 0], o);
                o = fmaf(h4.y, Wreg[4 * k4 + 1], o);
                o = fmaf(h4.z, Wreg[4 * k4 + 2], o);
                o = fmaf(h4.w, Wreg[4 * k4 + 3], o);
            }
            g1[(size_t)w * FDIM + j] = __float2bfloat16(dis[w] * o);
            __threadfence_block();
        }
    }
}

// --- lean gather: a[w][j] = relu(dis[w]*(g[w][j]+Σ g[r][j]))  (bf16 out) ---
__global__ __launch_bounds__(256, 8)
void k_gather(const int* __restrict__ rows4, const int* __restrict__ off,
              const float* __restrict__ dis, const bf16* __restrict__ g,
              bf16* __restrict__ a, int n) {
    int t = blockIdx.x * blockDim.x + threadIdx.x;
    int w = t >> 6, j = t & 63;
    if (w >= n) return;
    float acc0 = __bfloat162float(g[(size_t)w * FDIM + j]);  // self loop
    float acc1 = 0.0f;
    int k = off[w], e = off[w + 1];
    for (; k + 8 <= e; k += 8) {
        int r0 = rows4[k], r1 = rows4[k + 1], r2 = rows4[k + 2], r3 = rows4[k + 3];
        int r4 = rows4[k + 4], r5 = rows4[k + 5], r6 = rows4[k + 6], r7 = rows4[k + 7];
        float h0 = __bfloat162float(g[(size_t)r0 * FDIM + j]);
        float h1 = __bfloat162float(g[(size_t)r1 * FDIM + j]);
        float h2 = __bfloat162float(g[(size_t)r2 * FDIM + j]);
        float h3 = __bfloat162float(g[(size_t)r3 * FDIM + j]);
        float h4 = __bfloat162float(g[(size_t)r4 * FDIM + j]);
        float h5 = __bfloat162float(g[(size_t)r5 * FDIM + j]);
        float h6 = __bfloat162float(g[(size_t)r6 * FDIM + j]);
        float h7 = __bfloat162float(g[(size_t)r7 * FDIM + j]);
        acc0 += h0; acc1 += h1; acc0 += h2; acc1 += h3;
        acc0 += h4; acc1 += h5; acc0 += h6; acc1 += h7;
    }
    for (; k + 2 <= e; k += 2) {
        int r0 = rows4[k], r1 = rows4[k + 1];
        acc0 += __bfloat162float(g[(size_t)r0 * FDIM + j]);
        acc1 += __bfloat162float(g[(size_t)r1 * FDIM + j]);
    }
    if (k < e) acc0 += __bfloat162float(g[(size_t)rows4[k] * FDIM + j]);
    a[(size_t)w * FDIM + j] = __float2bfloat16(fmaxf(dis[w] * (acc0 + acc1), 0.0f));
}

// --- MFMA matvec: o = A@W + b ; FINAL ? relu(o) f32 : bf16(dis*o) ---
// Layouts (guide-verified): A-frag A[m=lane&15][k=quad*8+j];
// B-frag B[k=quad*8+j][n=lane&15]; C/D: n=lane&15, m=quad*4+reg.
template <bool FINAL>
__global__ __launch_bounds__(256, 4)
void k_mat(const bf16* __restrict__ A, const float* __restrict__ W,
           const float* __restrict__ bvec, const float* __restrict__ dis,
           void* __restrict__ outp, int n) {
    __shared__ __align__(16) bf16 sWt[FDIM * FDIM];   // Wt[n][k] (transposed)
    int t = threadIdx.x;
    for (int idx = t; idx < FDIM * FDIM; idx += 256) {
        int kk = idx >> 6, nn = idx & 63;
        sWt[nn * FDIM + kk] = __float2bfloat16(W[idx]);
    }
    __syncthreads();
    int wave = t >> 6, lane = t & 63;
    int quad = lane >> 4, l15 = lane & 15;
    v8s bfr[4][2];
    #pragma unroll
    for (int nt = 0; nt < 4; ++nt) {
        #pragma unroll
        for (int kf = 0; kf < 2; ++kf)
            bfr[nt][kf] = *(const v8s*)&sWt[(nt * 16 + l15) * FDIM + kf * 32 + quad * 8];
    }
    float bj[4];
    #pragma unroll
    for (int nt = 0; nt < 4; ++nt) bj[nt] = bvec[nt * 16 + l15];

    int ntiles = (n + 15) >> 4;
    int step = gridDim.x * 4;
    for (int tile = blockIdx.x * 4 + wave; tile < ntiles; tile += step) {
        int m0 = tile << 4;
        int mA = m0 + l15; if (mA >= n) mA = n - 1;
        v8s af0 = *(const v8s*)&A[(size_t)mA * FDIM + quad * 8];
        v8s af1 = *(const v8s*)&A[(size_t)mA * FDIM + 32 + quad * 8];
        v4f acc[4];
        #pragma unroll
        for (int nt = 0; nt < 4; ++nt) {
            acc[nt] = (v4f){0.f, 0.f, 0.f, 0.f};
            acc[nt] = __builtin_amdgcn_mfma_f32_16x16x32_bf16(af0, bfr[nt][0], acc[nt], 0, 0, 0);
            acc[nt] = __builtin_amdgcn_mfma_f32_16x16x32_bf16(af1, bfr[nt][1], acc[nt], 0, 0, 0);
        }
        #pragma unroll
        for (int r = 0; r < 4; ++r) {
            int node = m0 + quad * 4 + r;
            if (node >= n) continue;
            float dv = FINAL ? 0.0f : dis[node];
            #pragma unroll
            for (int nt = 0; nt < 4; ++nt) {
                int j = nt * 16 + l15;
                float o = acc[nt][r] + bj[nt];
                if (FINAL) ((float*)outp)[(size_t)node * FDIM + j] = fmaxf(o, 0.0f);
                else ((bf16*)outp)[(size_t)node * FDIM + j] = __float2bfloat16(dv * o);
            }
        }
    }
}

extern "C" void kernel_launch(void* const* d_in, const int* in_sizes, int n_in,
                              void* d_out, int out_size, void* d_ws, size_t ws_size,
                              hipStream_t stream) {
    const float* x    = (const float*)d_in[0];
    const float* feat = (const float*)d_in[1];
    const int*   ei   = (const int*)d_in[2];
    const float* W1   = (const float*)d_in[3];
    const float* b1   = (const float*)d_in[4];
    const float* W2   = (const float*)d_in[5];
    const float* b2   = (const float*)d_in[6];
    const float* Wfc  = (const float*)d_in[7];
    const float* bfc  = (const float*)d_in[8];
    float* out = (float*)d_out;

    const int n = in_sizes[0] / 32;   // 100000
    const int E = in_sizes[2] / 2;    // 1600000
    const int* row = ei;
    const int* col = ei + E;

    const int psize = (n + NPART - 1) / NPART;   // 12500
    const int P  = (n + BW - 1) / BW;            // 196
    const int CH = (E + NB - 1) / NB;            // 6250
    const int total = P * NB;                    // 50176
    const int ndis = (n + 255) / 256;            // 391

    // ws: off[n+1] | dis[n] | M[total] | bsum[256] | s4[E] | rows4[E]
    //     | (16B-aligned) bufA(bf16 64n) | bufB(bf16 64n)
    // part (512*psize u32 = 25.6 MB) aliases bufA+bufB (consumed in k_ds1
    // before k_fl writes bufA).
    int*   off  = (int*)d_ws;
    float* dis  = (float*)(off + (size_t)n + 1);
    int*   M    = (int*)(dis + n);
    int*   bsum = M + (size_t)total;
    int*   s4    = bsum + 256;
    int*   rows4 = s4 + E;
    size_t co = (size_t)(rows4 + E - (int*)d_ws);
    co = (co + 3) & ~(size_t)3;                  // 16B align for v8s loads
    bf16*  bufA  = (bf16*)((int*)d_ws + co);
    bf16*  bufB  = bufA + (size_t)n * FDIM;
    unsigned* part = (unsigned*)bufA;

    const int B = 256;

    k_h<<<NPART * GPB + NB, B, 0, stream>>>(row, col, part, M, E, n, psize, P, CH);
    k_ds1<<<ndis + P, B, 0, stream>>>(part, dis, M, bsum, n, psize, ndis, P);
    k_csc<<<NB, B, 0, stream>>>(row, col, M, bsum, s4, E, CH, P);
    k_fl<<<P + GPLIN, B, 0, stream>>>(s4, M, bsum, rows4, off,
                                      x, feat, W1, b1, dis, bufA, n, E, P);
    // layer 2: gather(g1)->a1 ; mat: g2 = bf16(dis*(a1@W2+b2))
    k_gather<<<(n + 3) / 4, B, 0, stream>>>(rows4, off, dis, bufA, bufB, n);
    k_mat<false><<<512, B, 0, stream>>>(bufB, W2, b2, dis, bufA, n);
    // fc: gather(g2)->a2 ; out = relu(a2@Wfc+bfc)
    k_gather<<<(n + 3) / 4, B, 0, stream>>>(rows4, off, dis, bufA, bufB, n);
    k_mat<true><<<512, B, 0, stream>>>(bufB, Wfc, bfc, dis, out, n);
}